// Round 2
// baseline (286.588 us; speedup 1.0000x reference)
//
#include <hip/hip_runtime.h>
#include <hip/hip_bf16.h>

// B=32, C=256, H=36, W=64, n=4096.  P = H*W = 2304.  NCOL = B*C = 8192.
#define P_HW   2304
#define NG     4096
#define NCOL   8192
#define KDIM   P_HW
#define NT     72          // K-tiles of 32: 2304/32

typedef __bf16 bf16x8 __attribute__((ext_vector_type(8)));
typedef float  f32x4  __attribute__((ext_vector_type(4)));

__device__ __forceinline__ unsigned short f2bf(float f) {
    union { float f; unsigned int u; } x; x.f = f;
    unsigned int r = x.u + 0x7FFFu + ((x.u >> 16) & 1u);   // RNE
    return (unsigned short)(r >> 16);
}

// ---------------------------------------------------------------------------
// Fused prep: UNCHANGED from baseline (isolates the GEMM change).
// ---------------------------------------------------------------------------
__global__ __launch_bounds__(256) void prep_kernel(
    const float* __restrict__ feat,
    const float* __restrict__ mu,
    const float* __restrict__ logsx,
    const float* __restrict__ logsy,
    const float* __restrict__ rho,
    unsigned short* __restrict__ F,
    unsigned short* __restrict__ G,
    float* __restrict__ out) {
    const int bid = blockIdx.x;
    const int tid = threadIdx.x;
    if (bid < 9216) {
        const size_t i = ((size_t)bid * 256 + tid) * 8;
        const float4 v0 = *(const float4*)(feat + i);
        const float4 v1 = *(const float4*)(feat + i + 4);
        union { unsigned short s[8]; uint4 q; } o;
        o.s[0] = f2bf(v0.x); o.s[1] = f2bf(v0.y); o.s[2] = f2bf(v0.z); o.s[3] = f2bf(v0.w);
        o.s[4] = f2bf(v1.x); o.s[5] = f2bf(v1.y); o.s[6] = f2bf(v1.z); o.s[7] = f2bf(v1.w);
        *(uint4*)(F + i) = o.q;
    } else if (bid < 13312) {
        const int n = bid - 9216;
        const float mux = mu[2 * n], muy = mu[2 * n + 1];
        const float sx = __expf(logsx[n]) + 1e-6f;
        const float sy = __expf(logsy[n]) + 1e-6f;
        const float r  = tanhf(rho[n]);
        const float inv_den = 1.0f / (2.0f * (1.0f - r * r + 1e-6f));
        const float isx = 1.0f / sx, isy = 1.0f / sy;
        for (int base = tid * 8; base < P_HW; base += 2048) {
            const int h = base >> 6, w0 = base & 63;      // W = 64
            const float Y  = -1.0f + (float)h * (2.0f / 35.0f);
            const float yc = (Y - muy) * isy;
            union { unsigned short s[8]; uint4 q; } o;
#pragma unroll
            for (int j = 0; j < 8; ++j) {
                const float X  = -1.0f + (float)(w0 + j) * (2.0f / 63.0f);
                const float xc = (X - mux) * isx;
                const float A  = xc * xc + yc * yc - 2.0f * r * xc * yc;
                o.s[j] = f2bf(__expf(-A * inv_den));
            }
            *(uint4*)&G[(size_t)n * P_HW + base] = o.q;
        }
    } else {
        const size_t i = ((size_t)(bid - 13312) * 256 + tid) * 8;
        const float4 z = {0.f, 0.f, 0.f, 0.f};
        *(float4*)(out + i)     = z;
        *(float4*)(out + i + 4) = z;
    }
}

// ---------------------------------------------------------------------------
// GEMM v2: 256x256 tile, BK=32, 8 waves (2Mx4N), 4-deep LDS ring (128 KiB),
// phase-split K-loop with counted vmcnt(8) (never 0 in the main loop) +
// setprio around MFMA clusters.  T2 XOR swizzle carried over from baseline.
// 256-wide col tile spans exactly one b -> plain stores, no atomics.
// ---------------------------------------------------------------------------
__device__ __forceinline__ void async16(const void* g, void* l) {
    __builtin_amdgcn_global_load_lds(
        (__attribute__((address_space(1))) void*)(unsigned long long)g,
        (__attribute__((address_space(3))) void*)(unsigned int)(unsigned long long)l,
        16, 0, 0);
}

__global__ __launch_bounds__(512, 2) void gemm_fused(
    const unsigned short* __restrict__ G,   // [NG][K] bf16
    const unsigned short* __restrict__ F,   // [NCOL][K] bf16
    const float* __restrict__ weight,       // [NG][256] fp32
    float* __restrict__ out)                // [32][NG] fp32
{
    // 4 ring buffers; each: A[256][32] (8192 elems) + B[256][32] (8192 elems).
    // Within a tile: row stride 32 elems (64 B), 4 chunks/row of 8 bf16.
    // LDS slot (r, cp) holds global chunk c = cp ^ (r&3)  [XOR swizzle].
    __shared__ __align__(16) unsigned short lds[4 * 16384];

    const int tid  = threadIdx.x;            // 0..511
    const int lane = tid & 63;
    const int wid  = tid >> 6;               // 0..7
    const int wr   = wid >> 2;               // 0..1  (M half: 128 rows)
    const int wc   = wid & 3;                // 0..3  (N quarter: 64 cols)
    const int quad = lane >> 4, m = lane & 15;

    const int rowBase = blockIdx.y * 256;    // over NG
    const int colBase = blockIdx.x * 256;    // over NCOL (= b*256, full C range)

    // Staging: per tile 1024 chunks of 16B; thread t, round i: slot s=i*512+t,
    // r=s>>2 = i*128+(t>>2), c_lds=s&3=t&3, global chunk c=(t&3)^(r&3);
    // r&3=(t>>2)&3 is i-invariant -> per-i offset is the constant 128*KDIM.
    const int rA = tid >> 2;
    const int cA = (tid & 3) ^ (rA & 3);
    const unsigned short* pA = G + (size_t)(rowBase + rA) * KDIM + cA * 8;
    const unsigned short* pB = F + (size_t)(colBase + rA) * KDIM + cA * 8;

    // ds_read offsets: row = band + m, chunk cp = quad ^ (row&3) = quad ^ (m&3)
    const int sw   = (quad ^ (m & 3)) * 8;
    const int aoff = (wr * 128 + m) * 32 + sw;
    const int boff = (wc * 64  + m) * 32 + sw;

    f32x4 acc[8][4];
#pragma unroll
    for (int i = 0; i < 8; ++i)
#pragma unroll
        for (int j = 0; j < 4; ++j)
            acc[i][j] = (f32x4){0.f, 0.f, 0.f, 0.f};

    // Prologue: stage tiles 0,1,2 (4 gloads each); wait tile 0 (leave 8).
#pragma unroll
    for (int t = 0; t < 3; ++t) {
        const int bo = t * 16384;
#pragma unroll
        for (int i = 0; i < 2; ++i)
            async16(pA + t * 32 + i * (128 * KDIM), &lds[bo + i * 4096 + tid * 8]);
#pragma unroll
        for (int i = 0; i < 2; ++i)
            async16(pB + t * 32 + i * (128 * KDIM), &lds[bo + 8192 + i * 4096 + tid * 8]);
    }
    asm volatile("s_waitcnt vmcnt(8)" ::: "memory");
    __builtin_amdgcn_s_barrier();

    // Main loop: tile t from buf t&3; prefetch tile (t+3)%NT into buf (t+3)&3.
    // (NT%4==0 so the wrapped prefetches land in consumed buffers — garbage
    //  that is never read; drained by vmcnt(0) before the epilogue.)
    for (int t = 0; t < NT; ++t) {
        const int bo  = (t & 3) * 16384;
        const int w   = (t + 3 >= NT) ? (t + 3 - NT) : (t + 3);
        const int wbo = (w & 3) * 16384;
        const unsigned short* pAw = pA + w * 32;
        const unsigned short* pBw = pB + w * 32;

        bf16x8 a[4], b[4];
        // ---------------- phase A: rows [wr*128, +64) x all 4 j ----------
#pragma unroll
        for (int i = 0; i < 4; ++i)
            a[i] = *(const bf16x8*)&lds[bo + aoff + i * 512];
#pragma unroll
        for (int j = 0; j < 4; ++j)
            b[j] = *(const bf16x8*)&lds[bo + 8192 + boff + j * 512];
#pragma unroll
        for (int i = 0; i < 2; ++i)
            async16(pAw + i * (128 * KDIM), &lds[wbo + i * 4096 + tid * 8]);
        __builtin_amdgcn_sched_barrier(0);
        __builtin_amdgcn_s_barrier();
        asm volatile("s_waitcnt lgkmcnt(0)" ::: "memory");
        __builtin_amdgcn_sched_barrier(0);
        __builtin_amdgcn_s_setprio(1);
#pragma unroll
        for (int i = 0; i < 4; ++i)
#pragma unroll
            for (int j = 0; j < 4; ++j)
                acc[i][j] = __builtin_amdgcn_mfma_f32_16x16x32_bf16(a[i], b[j], acc[i][j], 0, 0, 0);
        __builtin_amdgcn_s_setprio(0);
        __builtin_amdgcn_sched_barrier(0);
        __builtin_amdgcn_s_barrier();
        __builtin_amdgcn_sched_barrier(0);
        // ---------------- phase B: rows [wr*128+64, +64) x all 4 j -------
#pragma unroll
        for (int i = 0; i < 4; ++i)
            a[i] = *(const bf16x8*)&lds[bo + aoff + (i + 4) * 512];
#pragma unroll
        for (int i = 0; i < 2; ++i)
            async16(pBw + i * (128 * KDIM), &lds[wbo + 8192 + i * 4096 + tid * 8]);
        __builtin_amdgcn_sched_barrier(0);
        __builtin_amdgcn_s_barrier();
        asm volatile("s_waitcnt lgkmcnt(0)" ::: "memory");
        __builtin_amdgcn_sched_barrier(0);
        __builtin_amdgcn_s_setprio(1);
#pragma unroll
        for (int i = 0; i < 4; ++i)
#pragma unroll
            for (int j = 0; j < 4; ++j)
                acc[i + 4][j] = __builtin_amdgcn_mfma_f32_16x16x32_bf16(a[i], b[j], acc[i + 4][j], 0, 0, 0);
        __builtin_amdgcn_s_setprio(0);
        // Counted wait: leave the 2 newest prefetch groups (8 loads) in flight;
        // guarantees tile t+1 has landed before the next iteration reads it.
        asm volatile("s_waitcnt vmcnt(8)" ::: "memory");
        __builtin_amdgcn_sched_barrier(0);
        __builtin_amdgcn_s_barrier();
        __builtin_amdgcn_sched_barrier(0);
    }

    // Drain garbage prefetches before reusing LDS for the reduction.
    asm volatile("s_waitcnt vmcnt(0)" ::: "memory");
    __syncthreads();

    // Epilogue: out[b][n] = sum_c pooled[n][b*256+c] * weight[n][c].
    // acc[i][j][reg] = pooled[rowBase + wr*128 + i*16 + quad*4 + reg]
    //                        [colBase + wc*64 + j*16 + m]
    float* red = (float*)lds;                // [4 wc][256 n_local]
    const int cwbase = wc * 64 + m;
#pragma unroll
    for (int i = 0; i < 8; ++i) {
#pragma unroll
        for (int reg = 0; reg < 4; ++reg) {
            const int nloc = wr * 128 + i * 16 + quad * 4 + reg;
            const float* wrow = weight + (size_t)(rowBase + nloc) * 256 + cwbase;
            float s = 0.f;
#pragma unroll
            for (int j = 0; j < 4; ++j)
                s += acc[i][j][reg] * wrow[j * 16];
            s += __shfl_xor(s, 1);
            s += __shfl_xor(s, 2);
            s += __shfl_xor(s, 4);
            s += __shfl_xor(s, 8);
            if (m == 0)
                red[wc * 256 + nloc] = s;
        }
    }
    __syncthreads();
    if (tid < 256) {
        const float s = red[tid] + red[256 + tid] + red[512 + tid] + red[768 + tid];
        out[(size_t)blockIdx.x * NG + rowBase + tid] = s;
    }
}

// ---------------------------------------------------------------------------
extern "C" void kernel_launch(void* const* d_in, const int* in_sizes, int n_in,
                              void* d_out, int out_size, void* d_ws, size_t ws_size,
                              hipStream_t stream) {
    const float* feat   = (const float*)d_in[0];
    const float* mu     = (const float*)d_in[1];
    const float* logsx  = (const float*)d_in[2];
    const float* logsy  = (const float*)d_in[3];
    const float* rho    = (const float*)d_in[4];
    const float* weight = (const float*)d_in[5];
    float* out = (float*)d_out;

    unsigned short* Gbuf = (unsigned short*)d_ws;                  // 4096*2304*2 B
    unsigned short* Fbuf = Gbuf + (size_t)NG * P_HW;               // 8192*2304*2 B

    hipLaunchKernelGGL(prep_kernel, dim3(13376), dim3(256), 0, stream,
                       feat, mu, logsx, logsy, rho, Fbuf, Gbuf, out);

    hipLaunchKernelGGL(gemm_fused, dim3(NCOL / 256, NG / 256), dim3(512), 0, stream,
                       Gbuf, Fbuf, weight, out);
}

// Round 3
// 271.569 us; speedup vs baseline: 1.0553x; 1.0553x over previous
//
#include <hip/hip_runtime.h>
#include <hip/hip_bf16.h>

// B=32, C=256, H=36, W=64, n=4096.  P = H*W = 2304.  NCOL = B*C = 8192.
#define P_HW   2304
#define NG     4096
#define NCOL   8192
#define KDIM   P_HW
#define NT     72          // K-tiles of 32: 2304/32

typedef __bf16 bf16x8 __attribute__((ext_vector_type(8)));
typedef float  f32x4  __attribute__((ext_vector_type(4)));

__device__ __forceinline__ unsigned short f2bf(float f) {
    union { float f; unsigned int u; } x; x.f = f;
    unsigned int r = x.u + 0x7FFFu + ((x.u >> 16) & 1u);   // RNE
    return (unsigned short)(r >> 16);
}

// ---------------------------------------------------------------------------
// Fused prep: UNCHANGED from baseline.
// ---------------------------------------------------------------------------
__global__ __launch_bounds__(256) void prep_kernel(
    const float* __restrict__ feat,
    const float* __restrict__ mu,
    const float* __restrict__ logsx,
    const float* __restrict__ logsy,
    const float* __restrict__ rho,
    unsigned short* __restrict__ F,
    unsigned short* __restrict__ G,
    float* __restrict__ out) {
    const int bid = blockIdx.x;
    const int tid = threadIdx.x;
    if (bid < 9216) {
        const size_t i = ((size_t)bid * 256 + tid) * 8;
        const float4 v0 = *(const float4*)(feat + i);
        const float4 v1 = *(const float4*)(feat + i + 4);
        union { unsigned short s[8]; uint4 q; } o;
        o.s[0] = f2bf(v0.x); o.s[1] = f2bf(v0.y); o.s[2] = f2bf(v0.z); o.s[3] = f2bf(v0.w);
        o.s[4] = f2bf(v1.x); o.s[5] = f2bf(v1.y); o.s[6] = f2bf(v1.z); o.s[7] = f2bf(v1.w);
        *(uint4*)(F + i) = o.q;
    } else if (bid < 13312) {
        const int n = bid - 9216;
        const float mux = mu[2 * n], muy = mu[2 * n + 1];
        const float sx = __expf(logsx[n]) + 1e-6f;
        const float sy = __expf(logsy[n]) + 1e-6f;
        const float r  = tanhf(rho[n]);
        const float inv_den = 1.0f / (2.0f * (1.0f - r * r + 1e-6f));
        const float isx = 1.0f / sx, isy = 1.0f / sy;
        for (int base = tid * 8; base < P_HW; base += 2048) {
            const int h = base >> 6, w0 = base & 63;      // W = 64
            const float Y  = -1.0f + (float)h * (2.0f / 35.0f);
            const float yc = (Y - muy) * isy;
            union { unsigned short s[8]; uint4 q; } o;
#pragma unroll
            for (int j = 0; j < 8; ++j) {
                const float X  = -1.0f + (float)(w0 + j) * (2.0f / 63.0f);
                const float xc = (X - mux) * isx;
                const float A  = xc * xc + yc * yc - 2.0f * r * xc * yc;
                o.s[j] = f2bf(__expf(-A * inv_den));
            }
            *(uint4*)&G[(size_t)n * P_HW + base] = o.q;
        }
    } else {
        const size_t i = ((size_t)(bid - 13312) * 256 + tid) * 8;
        const float4 z = {0.f, 0.f, 0.f, 0.f};
        *(float4*)(out + i)     = z;
        *(float4*)(out + i + 4) = z;
    }
}

// ---------------------------------------------------------------------------
// GEMM v3: identical to v2 EXCEPT the LDS swizzle.
// R2 post-mortem: with BK=32 (row = 64 B = half the 128 B bank wrap), the
// swizzle chunk^(row&3) gives slot (m&1, m&3) — period 4 in m — so each
// quarter-wave (fixed quad, m=0..15) hit only 4 of 8 bank slots => 4-way
// conflict (SQ_LDS_BANK_CONFLICT 0 -> 1.4e7).  Fix: chunk^((row>>1)&3):
// slot (m&1, (m>>1)&3) has period 8 => 8 slots, 2 lanes each = free (m136).
// Staging stays i-invariant: c = (tid&3) ^ ((tid>>3)&3); read side stays
// band-invariant since band is a multiple of 16.
// ---------------------------------------------------------------------------
__device__ __forceinline__ void async16(const void* g, void* l) {
    __builtin_amdgcn_global_load_lds(
        (__attribute__((address_space(1))) void*)(unsigned long long)g,
        (__attribute__((address_space(3))) void*)(unsigned int)(unsigned long long)l,
        16, 0, 0);
}

__global__ __launch_bounds__(512, 2) void gemm_fused(
    const unsigned short* __restrict__ G,   // [NG][K] bf16
    const unsigned short* __restrict__ F,   // [NCOL][K] bf16
    const float* __restrict__ weight,       // [NG][256] fp32
    float* __restrict__ out)                // [32][NG] fp32
{
    // 4 ring buffers; each: A[256][32] + B[256][32] bf16.
    // LDS slot (r, cp) holds global chunk c = cp ^ ((r>>1)&3)  [XOR swizzle].
    __shared__ __align__(16) unsigned short lds[4 * 16384];

    const int tid  = threadIdx.x;            // 0..511
    const int lane = tid & 63;
    const int wid  = tid >> 6;               // 0..7
    const int wr   = wid >> 2;               // 0..1  (M half: 128 rows)
    const int wc   = wid & 3;                // 0..3  (N quarter: 64 cols)
    const int quad = lane >> 4, m = lane & 15;

    const int rowBase = blockIdx.y * 256;    // over NG
    const int colBase = blockIdx.x * 256;    // over NCOL (= b*256, full C range)

    // Staging: thread t, round i: slot s=i*512+t -> r=i*128+(t>>2), cp=t&3;
    // global chunk c = cp ^ ((r>>1)&3) = (t&3) ^ ((t>>3)&3)   [i-invariant]
    const int rA = tid >> 2;
    const int cA = (tid & 3) ^ ((tid >> 3) & 3);
    const unsigned short* pA = G + (size_t)(rowBase + rA) * KDIM + cA * 8;
    const unsigned short* pB = F + (size_t)(colBase + rA) * KDIM + cA * 8;

    // ds_read: row = band + m (band mult of 16), chunk cp = quad ^ ((m>>1)&3)
    const int sw   = (quad ^ ((m >> 1) & 3)) * 8;
    const int aoff = (wr * 128 + m) * 32 + sw;
    const int boff = (wc * 64  + m) * 32 + sw;

    f32x4 acc[8][4];
#pragma unroll
    for (int i = 0; i < 8; ++i)
#pragma unroll
        for (int j = 0; j < 4; ++j)
            acc[i][j] = (f32x4){0.f, 0.f, 0.f, 0.f};

    // Prologue: stage tiles 0,1,2 (4 gloads each); wait tile 0 (leave 8).
#pragma unroll
    for (int t = 0; t < 3; ++t) {
        const int bo = t * 16384;
#pragma unroll
        for (int i = 0; i < 2; ++i)
            async16(pA + t * 32 + i * (128 * KDIM), &lds[bo + i * 4096 + tid * 8]);
#pragma unroll
        for (int i = 0; i < 2; ++i)
            async16(pB + t * 32 + i * (128 * KDIM), &lds[bo + 8192 + i * 4096 + tid * 8]);
    }
    asm volatile("s_waitcnt vmcnt(8)" ::: "memory");
    __builtin_amdgcn_s_barrier();

    // Main loop: tile t from buf t&3; prefetch tile (t+3)%NT into buf (t+3)&3.
    for (int t = 0; t < NT; ++t) {
        const int bo  = (t & 3) * 16384;
        const int w   = (t + 3 >= NT) ? (t + 3 - NT) : (t + 3);
        const int wbo = (w & 3) * 16384;
        const unsigned short* pAw = pA + w * 32;
        const unsigned short* pBw = pB + w * 32;

        bf16x8 a[4], b[4];
        // ---------------- phase A: rows [wr*128, +64) x all 4 j ----------
#pragma unroll
        for (int i = 0; i < 4; ++i)
            a[i] = *(const bf16x8*)&lds[bo + aoff + i * 512];
#pragma unroll
        for (int j = 0; j < 4; ++j)
            b[j] = *(const bf16x8*)&lds[bo + 8192 + boff + j * 512];
#pragma unroll
        for (int i = 0; i < 2; ++i)
            async16(pAw + i * (128 * KDIM), &lds[wbo + i * 4096 + tid * 8]);
        __builtin_amdgcn_sched_barrier(0);
        __builtin_amdgcn_s_barrier();
        asm volatile("s_waitcnt lgkmcnt(0)" ::: "memory");
        __builtin_amdgcn_sched_barrier(0);
        __builtin_amdgcn_s_setprio(1);
#pragma unroll
        for (int i = 0; i < 4; ++i)
#pragma unroll
            for (int j = 0; j < 4; ++j)
                acc[i][j] = __builtin_amdgcn_mfma_f32_16x16x32_bf16(a[i], b[j], acc[i][j], 0, 0, 0);
        __builtin_amdgcn_s_setprio(0);
        __builtin_amdgcn_sched_barrier(0);
        __builtin_amdgcn_s_barrier();
        __builtin_amdgcn_sched_barrier(0);
        // ---------------- phase B: rows [wr*128+64, +64) x all 4 j -------
#pragma unroll
        for (int i = 0; i < 4; ++i)
            a[i] = *(const bf16x8*)&lds[bo + aoff + (i + 4) * 512];
#pragma unroll
        for (int i = 0; i < 2; ++i)
            async16(pBw + i * (128 * KDIM), &lds[wbo + 8192 + i * 4096 + tid * 8]);
        __builtin_amdgcn_sched_barrier(0);
        __builtin_amdgcn_s_barrier();
        asm volatile("s_waitcnt lgkmcnt(0)" ::: "memory");
        __builtin_amdgcn_sched_barrier(0);
        __builtin_amdgcn_s_setprio(1);
#pragma unroll
        for (int i = 0; i < 4; ++i)
#pragma unroll
            for (int j = 0; j < 4; ++j)
                acc[i + 4][j] = __builtin_amdgcn_mfma_f32_16x16x32_bf16(a[i], b[j], acc[i + 4][j], 0, 0, 0);
        __builtin_amdgcn_s_setprio(0);
        // Counted wait: leave the 2 newest prefetch groups (8 loads) in flight.
        asm volatile("s_waitcnt vmcnt(8)" ::: "memory");
        __builtin_amdgcn_sched_barrier(0);
        __builtin_amdgcn_s_barrier();
        __builtin_amdgcn_sched_barrier(0);
    }

    // Drain garbage prefetches before reusing LDS for the reduction.
    asm volatile("s_waitcnt vmcnt(0)" ::: "memory");
    __syncthreads();

    // Epilogue: out[b][n] = sum_c pooled[n][b*256+c] * weight[n][c].
    float* red = (float*)lds;                // [4 wc][256 n_local]
    const int cwbase = wc * 64 + m;
#pragma unroll
    for (int i = 0; i < 8; ++i) {
#pragma unroll
        for (int reg = 0; reg < 4; ++reg) {
            const int nloc = wr * 128 + i * 16 + quad * 4 + reg;
            const float* wrow = weight + (size_t)(rowBase + nloc) * 256 + cwbase;
            float s = 0.f;
#pragma unroll
            for (int j = 0; j < 4; ++j)
                s += acc[i][j][reg] * wrow[j * 16];
            s += __shfl_xor(s, 1);
            s += __shfl_xor(s, 2);
            s += __shfl_xor(s, 4);
            s += __shfl_xor(s, 8);
            if (m == 0)
                red[wc * 256 + nloc] = s;
        }
    }
    __syncthreads();
    if (tid < 256) {
        const float s = red[tid] + red[256 + tid] + red[512 + tid] + red[768 + tid];
        out[(size_t)blockIdx.x * NG + rowBase + tid] = s;
    }
}

// ---------------------------------------------------------------------------
extern "C" void kernel_launch(void* const* d_in, const int* in_sizes, int n_in,
                              void* d_out, int out_size, void* d_ws, size_t ws_size,
                              hipStream_t stream) {
    const float* feat   = (const float*)d_in[0];
    const float* mu     = (const float*)d_in[1];
    const float* logsx  = (const float*)d_in[2];
    const float* logsy  = (const float*)d_in[3];
    const float* rho    = (const float*)d_in[4];
    const float* weight = (const float*)d_in[5];
    float* out = (float*)d_out;

    unsigned short* Gbuf = (unsigned short*)d_ws;                  // 4096*2304*2 B
    unsigned short* Fbuf = Gbuf + (size_t)NG * P_HW;               // 8192*2304*2 B

    hipLaunchKernelGGL(prep_kernel, dim3(13376), dim3(256), 0, stream,
                       feat, mu, logsx, logsy, rho, Fbuf, Gbuf, out);

    hipLaunchKernelGGL(gemm_fused, dim3(NCOL / 256, NG / 256), dim3(512), 0, stream,
                       Gbuf, Fbuf, weight, out);
}

// Round 4
// 270.272 us; speedup vs baseline: 1.0604x; 1.0048x over previous
//
#include <hip/hip_runtime.h>
#include <hip/hip_bf16.h>

// B=32, C=256, H=36, W=64, n=4096.  P = H*W = 2304.  NCOL = B*C = 8192.
#define P_HW   2304
#define NG     4096
#define NCOL   8192
#define KDIM   P_HW
#define NT     72          // K-tiles of 32: 2304/32

typedef __bf16 bf16x8 __attribute__((ext_vector_type(8)));
typedef float  f32x4  __attribute__((ext_vector_type(4)));

__device__ __forceinline__ unsigned short f2bf(float f) {
    union { float f; unsigned int u; } x; x.f = f;
    unsigned int r = x.u + 0x7FFFu + ((x.u >> 16) & 1u);   // RNE
    return (unsigned short)(r >> 16);
}

// ---------------------------------------------------------------------------
// Fused prep: UNCHANGED from baseline.
// ---------------------------------------------------------------------------
__global__ __launch_bounds__(256) void prep_kernel(
    const float* __restrict__ feat,
    const float* __restrict__ mu,
    const float* __restrict__ logsx,
    const float* __restrict__ logsy,
    const float* __restrict__ rho,
    unsigned short* __restrict__ F,
    unsigned short* __restrict__ G,
    float* __restrict__ out) {
    const int bid = blockIdx.x;
    const int tid = threadIdx.x;
    if (bid < 9216) {
        const size_t i = ((size_t)bid * 256 + tid) * 8;
        const float4 v0 = *(const float4*)(feat + i);
        const float4 v1 = *(const float4*)(feat + i + 4);
        union { unsigned short s[8]; uint4 q; } o;
        o.s[0] = f2bf(v0.x); o.s[1] = f2bf(v0.y); o.s[2] = f2bf(v0.z); o.s[3] = f2bf(v0.w);
        o.s[4] = f2bf(v1.x); o.s[5] = f2bf(v1.y); o.s[6] = f2bf(v1.z); o.s[7] = f2bf(v1.w);
        *(uint4*)(F + i) = o.q;
    } else if (bid < 13312) {
        const int n = bid - 9216;
        const float mux = mu[2 * n], muy = mu[2 * n + 1];
        const float sx = __expf(logsx[n]) + 1e-6f;
        const float sy = __expf(logsy[n]) + 1e-6f;
        const float r  = tanhf(rho[n]);
        const float inv_den = 1.0f / (2.0f * (1.0f - r * r + 1e-6f));
        const float isx = 1.0f / sx, isy = 1.0f / sy;
        for (int base = tid * 8; base < P_HW; base += 2048) {
            const int h = base >> 6, w0 = base & 63;      // W = 64
            const float Y  = -1.0f + (float)h * (2.0f / 35.0f);
            const float yc = (Y - muy) * isy;
            union { unsigned short s[8]; uint4 q; } o;
#pragma unroll
            for (int j = 0; j < 8; ++j) {
                const float X  = -1.0f + (float)(w0 + j) * (2.0f / 63.0f);
                const float xc = (X - mux) * isx;
                const float A  = xc * xc + yc * yc - 2.0f * r * xc * yc;
                o.s[j] = f2bf(__expf(-A * inv_den));
            }
            *(uint4*)&G[(size_t)n * P_HW + base] = o.q;
        }
    } else {
        const size_t i = ((size_t)(bid - 13312) * 256 + tid) * 8;
        const float4 z = {0.f, 0.f, 0.f, 0.f};
        *(float4*)(out + i)     = z;
        *(float4*)(out + i + 4) = z;
    }
}

// ---------------------------------------------------------------------------
// GEMM v4: free-run tile loop.  R3 post-mortem: lockstep phase barriers +
// 8 sched_barrier(0)/tile + runtime ring index cost ~1660 cyc/tile of
// non-MFMA time (MfmaUtil 38%).  v4: ONE vmcnt(8)+s_barrier per tile (the
// only cross-wave hazard is "tile t+1 landed"), x4 unroll makes all LDS
// bases static, no sched fences, no manual lgkmcnt — compiler pipelines
// 12 ds_reads into the 32-MFMA stream; 2 waves/SIMD drift within a tile
// so one wave's MFMA covers the other's reads (setprio arbitrates).
// Safety: vmcnt asm ("memory") fences reads from moving up; empty asm
// after s_barrier stops hoisting above the cross-wave completion point.
// ---------------------------------------------------------------------------
__device__ __forceinline__ void async16(const void* g, void* l) {
    __builtin_amdgcn_global_load_lds(
        (__attribute__((address_space(1))) void*)(unsigned long long)g,
        (__attribute__((address_space(3))) void*)(unsigned int)(unsigned long long)l,
        16, 0, 0);
}

__global__ __launch_bounds__(512, 2) void gemm_fused(
    const unsigned short* __restrict__ G,   // [NG][K] bf16
    const unsigned short* __restrict__ F,   // [NCOL][K] bf16
    const float* __restrict__ weight,       // [NG][256] fp32
    float* __restrict__ out)                // [32][NG] fp32
{
    // 4 ring buffers; each: A[256][32] + B[256][32] bf16.
    // LDS slot (r, cp) holds global chunk c = cp ^ ((r>>1)&3)  [XOR swizzle].
    __shared__ __align__(16) unsigned short lds[4 * 16384];

    const int tid  = threadIdx.x;            // 0..511
    const int lane = tid & 63;
    const int wid  = tid >> 6;               // 0..7
    const int wr   = wid >> 2;               // 0..1  (M half: 128 rows)
    const int wc   = wid & 3;                // 0..3  (N quarter: 64 cols)
    const int quad = lane >> 4, m = lane & 15;

    const int rowBase = blockIdx.y * 256;    // over NG
    const int colBase = blockIdx.x * 256;    // over NCOL (= b*256, full C range)

    // Staging: thread t, round i: slot s=i*512+t -> r=i*128+(t>>2), cp=t&3;
    // global chunk c = cp ^ ((r>>1)&3) = (t&3) ^ ((t>>3)&3)   [i-invariant]
    const int rA = tid >> 2;
    const int cA = (tid & 3) ^ ((tid >> 3) & 3);
    const unsigned short* pA = G + (size_t)(rowBase + rA) * KDIM + cA * 8;
    const unsigned short* pB = F + (size_t)(colBase + rA) * KDIM + cA * 8;

    // ds_read: row = band + m (band mult of 16), chunk cp = quad ^ ((m>>1)&3)
    const int sw   = (quad ^ ((m >> 1) & 3)) * 8;
    const int aoff = (wr * 128 + m) * 32 + sw;
    const int boff = (wc * 64  + m) * 32 + sw;

    f32x4 acc[8][4];
#pragma unroll
    for (int i = 0; i < 8; ++i)
#pragma unroll
        for (int j = 0; j < 4; ++j)
            acc[i][j] = (f32x4){0.f, 0.f, 0.f, 0.f};

    // Prologue: stage tiles 0,1,2 (4 gloads each); wait tile 0 (leave 8).
#pragma unroll
    for (int t = 0; t < 3; ++t) {
        const int bo = t * 16384;
        async16(pA + t * 32,                  &lds[bo + tid * 8]);
        async16(pA + t * 32 + 128 * KDIM,     &lds[bo + 4096 + tid * 8]);
        async16(pB + t * 32,                  &lds[bo + 8192 + tid * 8]);
        async16(pB + t * 32 + 128 * KDIM,     &lds[bo + 12288 + tid * 8]);
    }
    asm volatile("s_waitcnt vmcnt(8)" ::: "memory");
    __builtin_amdgcn_s_barrier();
    asm volatile("" ::: "memory");

    // Main loop: tile t from buf t&3; prefetch tile (t+3)%NT into buf (t+3)&3.
    // x4 unroll: t = tt+u with tt%4==0, so t&3 == u and (t+3)&3 == (u+3)&3
    // are compile-time -> all LDS bases static.
    for (int tt = 0; tt < NT; tt += 4) {
#pragma unroll
        for (int u = 0; u < 4; ++u) {
            const int t   = tt + u;
            const int bo  = u * 16384;               // static
            const int wbo = ((u + 3) & 3) * 16384;   // static
            int w = t + 3;
            if (w >= NT) w -= NT;                    // wrap: garbage into consumed buf
            const unsigned short* pAw = pA + w * 32;
            const unsigned short* pBw = pB + w * 32;

            // issue next-tile staging (4 gloads, stay in flight across tiles)
            async16(pAw,              &lds[wbo + tid * 8]);
            async16(pAw + 128 * KDIM, &lds[wbo + 4096 + tid * 8]);
            async16(pBw,              &lds[wbo + 8192 + tid * 8]);
            async16(pBw + 128 * KDIM, &lds[wbo + 12288 + tid * 8]);

            // 12 ds_reads + 32 MFMA; compiler interleaves via counted lgkmcnt
            bf16x8 a[8], b[4];
#pragma unroll
            for (int j = 0; j < 4; ++j)
                b[j] = *(const bf16x8*)&lds[bo + 8192 + boff + j * 512];
#pragma unroll
            for (int i = 0; i < 8; ++i)
                a[i] = *(const bf16x8*)&lds[bo + aoff + i * 512];

            __builtin_amdgcn_s_setprio(1);
#pragma unroll
            for (int i = 0; i < 8; ++i)
#pragma unroll
                for (int j = 0; j < 4; ++j)
                    acc[i][j] = __builtin_amdgcn_mfma_f32_16x16x32_bf16(a[i], b[j], acc[i][j], 0, 0, 0);
            __builtin_amdgcn_s_setprio(0);

            // Counted wait (never 0): leave tiles t+2,t+3 in flight; then the
            // barrier makes "tile t+1 landed" true for ALL waves' loads.
            asm volatile("s_waitcnt vmcnt(8)" ::: "memory");
            __builtin_amdgcn_s_barrier();
            asm volatile("" ::: "memory");
        }
    }

    // Drain garbage prefetches before reusing LDS for the reduction.
    asm volatile("s_waitcnt vmcnt(0)" ::: "memory");
    __syncthreads();

    // Epilogue: out[b][n] = sum_c pooled[n][b*256+c] * weight[n][c].
    float* red = (float*)lds;                // [4 wc][256 n_local]
    const int cwbase = wc * 64 + m;
#pragma unroll
    for (int i = 0; i < 8; ++i) {
#pragma unroll
        for (int reg = 0; reg < 4; ++reg) {
            const int nloc = wr * 128 + i * 16 + quad * 4 + reg;
            const float* wrow = weight + (size_t)(rowBase + nloc) * 256 + cwbase;
            float s = 0.f;
#pragma unroll
            for (int j = 0; j < 4; ++j)
                s += acc[i][j][reg] * wrow[j * 16];
            s += __shfl_xor(s, 1);
            s += __shfl_xor(s, 2);
            s += __shfl_xor(s, 4);
            s += __shfl_xor(s, 8);
            if (m == 0)
                red[wc * 256 + nloc] = s;
        }
    }
    __syncthreads();
    if (tid < 256) {
        const float s = red[tid] + red[256 + tid] + red[512 + tid] + red[768 + tid];
        out[(size_t)blockIdx.x * NG + rowBase + tid] = s;
    }
}

// ---------------------------------------------------------------------------
extern "C" void kernel_launch(void* const* d_in, const int* in_sizes, int n_in,
                              void* d_out, int out_size, void* d_ws, size_t ws_size,
                              hipStream_t stream) {
    const float* feat   = (const float*)d_in[0];
    const float* mu     = (const float*)d_in[1];
    const float* logsx  = (const float*)d_in[2];
    const float* logsy  = (const float*)d_in[3];
    const float* rho    = (const float*)d_in[4];
    const float* weight = (const float*)d_in[5];
    float* out = (float*)d_out;

    unsigned short* Gbuf = (unsigned short*)d_ws;                  // 4096*2304*2 B
    unsigned short* Fbuf = Gbuf + (size_t)NG * P_HW;               // 8192*2304*2 B

    hipLaunchKernelGGL(prep_kernel, dim3(13376), dim3(256), 0, stream,
                       feat, mu, logsx, logsy, rho, Fbuf, Gbuf, out);

    hipLaunchKernelGGL(gemm_fused, dim3(NCOL / 256, NG / 256), dim3(512), 0, stream,
                       Gbuf, Fbuf, weight, out);
}